// Round 10
// baseline (403.929 us; speedup 1.0000x reference)
//
#include <hip/hip_runtime.h>

#define N_NODES 100000
#define N_EDGES 1600000
#define NB      50
#define GSIZE   2000
#define FEAT    128
#define NC      10
#define BCAP    40960      // per-graph bucket capacity (mean 32000, sd ~177)
#define CHUNK   2048       // edges per binA block
#define NBLK_A  782        // ceil(E / CHUNK)
#define STAGE_CAP 12288    // binB stage (span mean 8000, sd ~89)

using short8 = __attribute__((ext_vector_type(8))) short;
using f32x4  = __attribute__((ext_vector_type(4))) float;

__device__ __forceinline__ unsigned bf16rnd(float f) {
    unsigned u = __float_as_uint(f);
    return (u + 0x7fffu + ((u >> 16) & 1u)) >> 16;   // RNE bf16 bits
}
__device__ __forceinline__ float blo(unsigned w) { return __uint_as_float(w << 16); }
__device__ __forceinline__ float bhi(unsigned w) { return __uint_as_float(w & 0xffff0000u); }

// XCD-pinned graph mapping: assumes XCD = blockIdx % 8 round-robin.
// XCD k owns graphs {k, k+8, ..., k+40} plus graph 48 (k=0) / 49 (k=1).
__device__ __forceinline__ int graph_of(int k, int gi) {
    if (gi < 6) return k + 8 * gi;
    return (k < 2) ? (48 + k) : -1;
}

// ---------------- phase A: bin edges into 50 per-graph buckets (LDS-staged) --------
__global__ __launch_bounds__(256) void k_binA(
    const int* __restrict__ src, const int* __restrict__ dst,
    unsigned* __restrict__ gbuf, int* __restrict__ gcur) {
    __shared__ int cnt[NB];
    __shared__ int base[NB];
    __shared__ int gbase[NB];
    __shared__ unsigned stage[CHUNK];
    __shared__ unsigned char bslot[CHUNK];
    __shared__ int total_s;
    int tid = threadIdx.x;
    int e0 = blockIdx.x * CHUNK;
    for (int i = tid; i < NB; i += 256) cnt[i] = 0;
    __syncthreads();

    unsigned pv[8]; int pb[8], pr[8];
#pragma unroll
    for (int q = 0; q < 8; ++q) {
        int e = e0 + q * 256 + tid;
        pb[q] = -1;
        if (e < N_EDGES) {
            int d = dst[e];
            int g = d / 2000;
            pv[q] = ((unsigned)src[e] << 11) | (unsigned)(d - g * 2000);
            pb[q] = g;
            pr[q] = atomicAdd(&cnt[g], 1);
        }
    }
    __syncthreads();
    if (tid == 0) {
        int run = 0;
        for (int b = 0; b < NB; ++b) { base[b] = run; run += cnt[b]; }
        total_s = run;
    }
    __syncthreads();
#pragma unroll
    for (int q = 0; q < 8; ++q) {
        if (pb[q] >= 0) {
            int s = base[pb[q]] + pr[q];
            stage[s] = pv[q];
            bslot[s] = (unsigned char)pb[q];
        }
    }
    if (tid < NB) gbase[tid] = atomicAdd(&gcur[tid], cnt[tid]);
    __syncthreads();
    int total = total_s;
    for (int s = tid; s < total; s += 256) {
        int b = bslot[s];
        gbuf[(size_t)b * BCAP + gbase[b] + (s - base[b])] = stage[s];
    }
}

// ---------------- per-graph: hist + scan -> rowstart, dinv, sdeg -------------------
__global__ __launch_bounds__(256) void k_prep(
    const unsigned* __restrict__ gbuf, const int* __restrict__ gcur,
    int* __restrict__ rowstart, float* __restrict__ dinv, float* __restrict__ sdeg) {
    __shared__ int hist[GSIZE];
    __shared__ int tsum[256];
    __shared__ int goff_s;
    int B = blockIdx.x; int k = B & 7, gi = B >> 3;
    int g = graph_of(k, gi);
    if (g < 0) return;
    int tid = threadIdx.x;
    for (int i = tid; i < GSIZE; i += 256) hist[i] = 0;
    if (tid == 0) { int run = 0; for (int i = 0; i < g; ++i) run += gcur[i]; goff_s = run; }
    __syncthreads();
    int n = gcur[g];
    const unsigned* bp = gbuf + (size_t)g * BCAP;
    for (int i = tid; i < n; i += 256) atomicAdd(&hist[bp[i] & 2047u], 1);
    __syncthreads();
    int base = tid * 8;
    int v[8]; int loc = 0;
#pragma unroll
    for (int q = 0; q < 8; ++q) {
        int idx = base + q;
        v[q] = (idx < GSIZE) ? hist[idx] : 0;
        loc += v[q];
    }
    tsum[tid] = loc; __syncthreads();
    for (int off = 1; off < 256; off <<= 1) {
        int t = (tid >= off) ? tsum[tid - off] : 0;
        __syncthreads(); tsum[tid] += t; __syncthreads();
    }
    int run = goff_s + tsum[tid] - loc;
#pragma unroll
    for (int q = 0; q < 8; ++q) {
        int idx = base + q;
        if (idx < GSIZE) {
            int node = g * GSIZE + idx;
            rowstart[node] = run;
            float d = fmaxf((float)v[q], 1.f);
            dinv[node] = rsqrtf(d);
            sdeg[node] = sqrtf(d);
            run += v[q];
        }
    }
    if (tid == 0) rowstart[g * GSIZE + GSIZE] = goff_s + n;  // == next graph's start
}

// ---------------- phase B: build csrc in LDS, write coalesced ----------------------
__global__ __launch_bounds__(256) void k_binB(
    const unsigned* __restrict__ gbuf, const int* __restrict__ gcur,
    const int* __restrict__ rowstart, int* __restrict__ csrc) {
    __shared__ int lcur[500];
    __shared__ int stage[STAGE_CAP];
    int B = blockIdx.x; int k = B & 7, j = B >> 3;
    int gi = j >> 2, q = j & 3;
    int g = graph_of(k, gi);
    if (g < 0) return;
    int tid = threadIdx.x;
    int n0 = g * GSIZE + q * 500;
    int n0l = q * 500;
    int span0 = rowstart[n0];
    int span  = rowstart[n0 + 500] - span0;
    for (int i = tid; i < 500; i += 256) lcur[i] = rowstart[n0 + i] - span0;
    __syncthreads();
    int n = gcur[g];
    const unsigned* bp = gbuf + (size_t)g * BCAP;
    for (int i = tid; i < n; i += 256) {
        unsigned v = bp[i];
        unsigned d = (v & 2047u) - (unsigned)n0l;
        if (d < 500u) {
            int p = atomicAdd(&lcur[d], 1);
            stage[p] = (int)(v >> 11);
        }
    }
    __syncthreads();
    for (int s = tid; s < span; s += 256)
        csrc[span0 + s] = stage[s];
}

// ---------------- convert: Yh = bf16(dinv * x) (XCD-pinned per graph) --------------
__global__ __launch_bounds__(256) void k_convert(const float* __restrict__ x,
                          const float* __restrict__ dinv, ushort* __restrict__ Yh) {
    int B = blockIdx.x; int k = B & 7, j = B >> 3;
    int gi = j / 250, local = j % 250;
    int g = graph_of(k, gi);
    if (g < 0) return;
    int tid = threadIdx.x;
    int r = tid >> 5, c = tid & 31;
    int node = g * GSIZE + local * 8 + r;
    float dv = dinv[node];
    float4 v = ((const float4*)x)[node * 32 + c];
    uint2 yo;
    yo.x = bf16rnd(v.x * dv) | (bf16rnd(v.y * dv) << 16);
    yo.y = bf16rnd(v.z * dv) | (bf16rnd(v.w * dv) << 16);
    ((uint2*)Yh)[node * 32 + c] = yo;
}

// ---------------- pack W (256x128) into MFMA B-fragment layout, hi/lo --------------
__global__ void k_packW(const float* __restrict__ W,
                        ushort* __restrict__ Wh, ushort* __restrict__ Wl) {
    int idx = blockIdx.x * 256 + threadIdx.x;   // 0..32767
    int j = idx & 7, l = (idx >> 3) & 63, kb = (idx >> 9) & 7, c = idx >> 12;
    int k = kb * 32 + (l >> 4) * 8 + j;
    int col = c * 16 + (l & 15);
    float w = W[k * 128 + col];
    unsigned h = bf16rnd(w);
    float rem = w - __uint_as_float(h << 16);
    Wh[idx] = (ushort)h;
    Wl[idx] = (ushort)bf16rnd(rem);
}

// ---------------- gather: T[n] = bf16( -dinv[n] * sum_e Yh[csrc[e]] ) --------------
// XCD-pinned: 16 nodes/block, 16 lanes/node, 16B loads. Row = 16 uint4 (256 B).
__global__ __launch_bounds__(256) void k_gather(
    const ushort* __restrict__ Yh, const float* __restrict__ dinv,
    const int* __restrict__ rowstart, const int* __restrict__ csrc,
    ushort* __restrict__ Th) {
    int B = blockIdx.x; int k = B & 7, j = B >> 3;
    int gi = j / 125, local = j % 125;
    int g = graph_of(k, gi);
    if (g < 0) return;
    int tid = threadIdx.x;
    int c = tid & 15;          // 16B column group 0..15
    int i = tid >> 4;          // node 0..15
    int n = g * GSIZE + local * 16 + i;
    int rs = rowstart[n], re = rowstart[n + 1];
    const uint4* Y4 = (const uint4*)Yh;
    float a0=0.f,a1=0.f,a2=0.f,a3=0.f,a4=0.f,a5=0.f,a6=0.f,a7=0.f;
    float d0=0.f,d1=0.f,d2=0.f,d3=0.f,d4=0.f,d5=0.f,d6=0.f,d7=0.f;
    int e = rs;
    for (; e + 1 < re; e += 2) {
        int s0 = csrc[e], s1 = csrc[e + 1];
        uint4 u = Y4[s0 * 16 + c];
        uint4 w = Y4[s1 * 16 + c];
        a0 += blo(u.x); a1 += bhi(u.x); a2 += blo(u.y); a3 += bhi(u.y);
        a4 += blo(u.z); a5 += bhi(u.z); a6 += blo(u.w); a7 += bhi(u.w);
        d0 += blo(w.x); d1 += bhi(w.x); d2 += blo(w.y); d3 += bhi(w.y);
        d4 += blo(w.z); d5 += bhi(w.z); d6 += blo(w.w); d7 += bhi(w.w);
    }
    if (e < re) {
        uint4 u = Y4[csrc[e] * 16 + c];
        a0 += blo(u.x); a1 += bhi(u.x); a2 += blo(u.y); a3 += bhi(u.y);
        a4 += blo(u.z); a5 += bhi(u.z); a6 += blo(u.w); a7 += bhi(u.w);
    }
    a0+=d0; a1+=d1; a2+=d2; a3+=d3; a4+=d4; a5+=d5; a6+=d6; a7+=d7;
    float dn = -dinv[n];
    uint4 o;
    o.x = bf16rnd(a0 * dn) | (bf16rnd(a1 * dn) << 16);
    o.y = bf16rnd(a2 * dn) | (bf16rnd(a3 * dn) << 16);
    o.z = bf16rnd(a4 * dn) | (bf16rnd(a5 * dn) << 16);
    o.w = bf16rnd(a6 * dn) | (bf16rnd(a7 * dn) << 16);
    ((uint4*)Th)[n * 16 + c] = o;
}

// ---------------- B-stationary MFMA GEMM (512 thr, 8 waves, 1 c-tile/wave) ----------
// out = relu(sdeg_row*(Y@Wa) + T@Wb + b). LOOP-INVERTED vs rounds 6-9: outer loop
// over K-slices (kb), inner over 5 row-tiles. Each B fragment is loaded ONCE and
// feeds 20 MFMAs while live only within one kb iteration (16 VGPRs) — the persistent
// state is the accumulators (40 VGPRs), which the compiler cannot sink. This kills
// the B-reload traffic that launch-bounds (r6) and asm-pinning (r9) failed to stop.
// mode 0: Oy = bf16(out * dinv[row]) -- MUST NOT alias Yh/Th (waves drift; no barrier).
// mode 1: fused segment-max into hg.
__global__ __launch_bounds__(512, 4) void k_gemm(
    const ushort* __restrict__ Yh, const ushort* __restrict__ Th,
    const ushort* __restrict__ Wh, const ushort* __restrict__ Wl,
    const float* __restrict__ bias, const float* __restrict__ dinv,
    const float* __restrict__ sdeg,
    ushort* __restrict__ Oy, float* __restrict__ hg, int mode) {
    int B = blockIdx.x; int k = B & 7, j = B >> 3;
    int gi = j / 25, local = j % 25;
    int g = graph_of(k, gi);
    if (g < 0) return;
    int tid = threadIdx.x;
    int lane = tid & 63, c = tid >> 6;      // wave index == c-tile
    int m = lane & 15, quad = lane >> 4;
    int rowbase = g * GSIZE + local * 80;
    int col = c * 16 + m;

    f32x4 accA[5], accB[5];
#pragma unroll
    for (int rt = 0; rt < 5; ++rt) {
        accA[rt] = (f32x4){0.f, 0.f, 0.f, 0.f};
        accB[rt] = (f32x4){0.f, 0.f, 0.f, 0.f};
    }

#pragma unroll 1
    for (int kb = 0; kb < 4; ++kb) {
        int boY = ((c * 8 + kb) * 64 + lane) * 8;
        int boT = ((c * 8 + kb + 4) * 64 + lane) * 8;
        short8 bhY = *reinterpret_cast<const short8*>(Wh + boY);
        short8 blY = *reinterpret_cast<const short8*>(Wl + boY);
        short8 bhT = *reinterpret_cast<const short8*>(Wh + boT);
        short8 blT = *reinterpret_cast<const short8*>(Wl + boT);
        int ko = kb * 32 + quad * 8;
        const ushort* pY = Yh + (rowbase + m) * FEAT + ko;
        const ushort* pT = Th + (rowbase + m) * FEAT + ko;
#pragma unroll
        for (int rt = 0; rt < 5; ++rt) {
            short8 aY = *reinterpret_cast<const short8*>(pY + rt * 16 * FEAT);
            short8 aT = *reinterpret_cast<const short8*>(pT + rt * 16 * FEAT);
            accA[rt] = __builtin_amdgcn_mfma_f32_16x16x32_bf16(aY, bhY, accA[rt], 0, 0, 0);
            accA[rt] = __builtin_amdgcn_mfma_f32_16x16x32_bf16(aY, blY, accA[rt], 0, 0, 0);
            accB[rt] = __builtin_amdgcn_mfma_f32_16x16x32_bf16(aT, bhT, accB[rt], 0, 0, 0);
            accB[rt] = __builtin_amdgcn_mfma_f32_16x16x32_bf16(aT, blT, accB[rt], 0, 0, 0);
        }
    }

    float bb = bias[col];
    if (mode == 0) {
#pragma unroll
        for (int rt = 0; rt < 5; ++rt) {
            int wrow = rowbase + rt * 16;
#pragma unroll
            for (int r = 0; r < 4; ++r) {
                int orow = wrow + quad * 4 + r;   // C/D: col = lane&15, row = quad*4 + reg
                float s = sdeg[orow], dv = dinv[orow];
                float v = fmaxf(accA[rt][r] * s + accB[rt][r] + bb, 0.f);
                Oy[orow * FEAT + col] = (ushort)bf16rnd(v * dv);
            }
        }
    } else {
        float run = 0.f;
#pragma unroll
        for (int rt = 0; rt < 5; ++rt) {
            int wrow = rowbase + rt * 16;
#pragma unroll
            for (int r = 0; r < 4; ++r) {
                float s = sdeg[wrow + quad * 4 + r];
                run = fmaxf(run, fmaxf(accA[rt][r] * s + accB[rt][r] + bb, 0.f));
            }
        }
        run = fmaxf(run, __shfl_xor(run, 16));
        run = fmaxf(run, __shfl_xor(run, 32));
        if (lane < 16)
            atomicMax((int*)&hg[g * FEAT + col], __float_as_int(run));  // vals >= 0, hg 0-init
    }
}

// ---------------- classifier ----------------
__global__ void k_classify(const float* __restrict__ hg, const float* __restrict__ Wc,
                           const float* __restrict__ bc, float* __restrict__ out) {
    int g = blockIdx.x, t = threadIdx.x;
    if (t < NC) {
        float acc = bc[t];
        for (int j = 0; j < FEAT; ++j) acc += hg[g * FEAT + j] * Wc[j * NC + t];
        out[g * NC + t] = acc;
    }
}

extern "C" void kernel_launch(void* const* d_in, const int* in_sizes, int n_in,
                              void* d_out, int out_size, void* d_ws, size_t ws_size,
                              hipStream_t stream) {
    const float* x   = (const float*)d_in[0];
    const float* W1  = (const float*)d_in[1];
    const float* b1  = (const float*)d_in[2];
    const float* W2  = (const float*)d_in[3];
    const float* b2  = (const float*)d_in[4];
    const float* Wc  = (const float*)d_in[5];
    const float* bc  = (const float*)d_in[6];
    const int*   src = (const int*)d_in[7];
    const int*   dst = (const int*)d_in[8];
    float* out = (float*)d_out;

    char* ws = (char*)d_ws;
    size_t off = 0;
    auto alloc = [&](size_t bytes) { char* p = ws + off; off += (bytes + 255) & ~(size_t)255; return p; };
    int*      gcur     = (int*)     alloc(NB * 4);            // contiguous with hg:
    float*    hg       = (float*)   alloc(NB * FEAT * 4);     // one memset covers both
    float*    dinv     = (float*)   alloc(N_NODES * 4);
    float*    sdeg     = (float*)   alloc(N_NODES * 4);
    int*      rowstart = (int*)     alloc((N_NODES + 1) * 4);
    unsigned* gbuf     = (unsigned*)alloc((size_t)NB * BCAP * 4);
    int*      csrc     = (int*)     alloc((size_t)N_EDGES * 4);
    ushort*   W1h      = (ushort*)  alloc(256 * 128 * 2);
    ushort*   W1l      = (ushort*)  alloc(256 * 128 * 2);
    ushort*   W2h      = (ushort*)  alloc(256 * 128 * 2);
    ushort*   W2l      = (ushort*)  alloc(256 * 128 * 2);
    ushort*   Yh       = (ushort*)  alloc((size_t)N_NODES * FEAT * 2);  // dinv*x (layer-1 A)
    ushort*   Y2h      = (ushort*)  alloc((size_t)N_NODES * FEAT * 2);  // dinv*h (layer-2 A)
    ushort*   Th       = (ushort*)  alloc((size_t)N_NODES * FEAT * 2);  // T1 -> T2

    hipMemsetAsync(gcur, 0, 256 + NB * FEAT * 4, stream);   // gcur + hg (adjacent)

    // CSR build
    k_binA<<<NBLK_A, 256, 0, stream>>>(src, dst, gbuf, gcur);
    k_prep<<<56, 256, 0, stream>>>(gbuf, gcur, rowstart, dinv, sdeg);
    k_binB<<<224, 256, 0, stream>>>(gbuf, gcur, rowstart, csrc);

    k_packW<<<128, 256, 0, stream>>>(W1, W1h, W1l);
    k_packW<<<128, 256, 0, stream>>>(W2, W2h, W2l);
    k_convert<<<14000, 256, 0, stream>>>(x, dinv, Yh);

    // layer 1 (gemm writes dinv*h into Y2h -- distinct buffer, no intra-block race)
    k_gather<<<7000, 256, 0, stream>>>(Yh, dinv, rowstart, csrc, Th);
    k_gemm<<<1400, 512, 0, stream>>>(Yh, Th, W1h, W1l, b1, dinv, sdeg, Y2h, nullptr, 0);
    // layer 2 (fused segmax)
    k_gather<<<7000, 256, 0, stream>>>(Y2h, dinv, rowstart, csrc, Th);
    k_gemm<<<1400, 512, 0, stream>>>(Y2h, Th, W2h, W2l, b2, dinv, sdeg, nullptr, hg, 1);

    k_classify<<<NB, 64, 0, stream>>>(hg, Wc, bc, out);
}

// Round 11
// 351.064 us; speedup vs baseline: 1.1506x; 1.1506x over previous
//
#include <hip/hip_runtime.h>

#define N_NODES 100000
#define N_EDGES 1600000
#define NB      50
#define GSIZE   2000
#define FEAT    128
#define NC      10
#define BCAP    40960      // per-graph bucket capacity (mean 32000, sd ~177)
#define CHUNK   2048       // edges per binA block
#define NBLK_A  782        // ceil(E / CHUNK)
#define STAGE_CAP 12288    // binB stage (span mean 8000, sd ~89)

using short8 = __attribute__((ext_vector_type(8))) short;
using f32x4  = __attribute__((ext_vector_type(4))) float;

__device__ __forceinline__ unsigned bf16rnd(float f) {
    unsigned u = __float_as_uint(f);
    return (u + 0x7fffu + ((u >> 16) & 1u)) >> 16;   // RNE bf16 bits
}
__device__ __forceinline__ float blo(unsigned w) { return __uint_as_float(w << 16); }
__device__ __forceinline__ float bhi(unsigned w) { return __uint_as_float(w & 0xffff0000u); }

// XCD-pinned graph mapping: assumes XCD = blockIdx % 8 round-robin.
// XCD k owns graphs {k, k+8, ..., k+40} plus graph 48 (k=0) / 49 (k=1).
__device__ __forceinline__ int graph_of(int k, int gi) {
    if (gi < 6) return k + 8 * gi;
    return (k < 2) ? (48 + k) : -1;
}

// ---------------- phase A: bin edges into 50 per-graph buckets (LDS-staged) --------
__global__ __launch_bounds__(256) void k_binA(
    const int* __restrict__ src, const int* __restrict__ dst,
    unsigned* __restrict__ gbuf, int* __restrict__ gcur) {
    __shared__ int cnt[NB];
    __shared__ int base[NB];
    __shared__ int gbase[NB];
    __shared__ unsigned stage[CHUNK];
    __shared__ unsigned char bslot[CHUNK];
    __shared__ int total_s;
    int tid = threadIdx.x;
    int e0 = blockIdx.x * CHUNK;
    for (int i = tid; i < NB; i += 256) cnt[i] = 0;
    __syncthreads();

    unsigned pv[8]; int pb[8], pr[8];
#pragma unroll
    for (int q = 0; q < 8; ++q) {
        int e = e0 + q * 256 + tid;
        pb[q] = -1;
        if (e < N_EDGES) {
            int d = dst[e];
            int g = d / 2000;
            pv[q] = ((unsigned)src[e] << 11) | (unsigned)(d - g * 2000);
            pb[q] = g;
            pr[q] = atomicAdd(&cnt[g], 1);
        }
    }
    __syncthreads();
    if (tid == 0) {
        int run = 0;
        for (int b = 0; b < NB; ++b) { base[b] = run; run += cnt[b]; }
        total_s = run;
    }
    __syncthreads();
#pragma unroll
    for (int q = 0; q < 8; ++q) {
        if (pb[q] >= 0) {
            int s = base[pb[q]] + pr[q];
            stage[s] = pv[q];
            bslot[s] = (unsigned char)pb[q];
        }
    }
    if (tid < NB) gbase[tid] = atomicAdd(&gcur[tid], cnt[tid]);
    __syncthreads();
    int total = total_s;
    for (int s = tid; s < total; s += 256) {
        int b = bslot[s];
        gbuf[(size_t)b * BCAP + gbase[b] + (s - base[b])] = stage[s];
    }
}

// ---------------- per-graph: hist + scan -> rowstart, dinv, sdeg -------------------
__global__ __launch_bounds__(256) void k_prep(
    const unsigned* __restrict__ gbuf, const int* __restrict__ gcur,
    int* __restrict__ rowstart, float* __restrict__ dinv, float* __restrict__ sdeg) {
    __shared__ int hist[GSIZE];
    __shared__ int tsum[256];
    __shared__ int goff_s;
    int B = blockIdx.x; int k = B & 7, gi = B >> 3;
    int g = graph_of(k, gi);
    if (g < 0) return;
    int tid = threadIdx.x;
    for (int i = tid; i < GSIZE; i += 256) hist[i] = 0;
    if (tid == 0) { int run = 0; for (int i = 0; i < g; ++i) run += gcur[i]; goff_s = run; }
    __syncthreads();
    int n = gcur[g];
    const unsigned* bp = gbuf + (size_t)g * BCAP;
    for (int i = tid; i < n; i += 256) atomicAdd(&hist[bp[i] & 2047u], 1);
    __syncthreads();
    int base = tid * 8;
    int v[8]; int loc = 0;
#pragma unroll
    for (int q = 0; q < 8; ++q) {
        int idx = base + q;
        v[q] = (idx < GSIZE) ? hist[idx] : 0;
        loc += v[q];
    }
    tsum[tid] = loc; __syncthreads();
    for (int off = 1; off < 256; off <<= 1) {
        int t = (tid >= off) ? tsum[tid - off] : 0;
        __syncthreads(); tsum[tid] += t; __syncthreads();
    }
    int run = goff_s + tsum[tid] - loc;
#pragma unroll
    for (int q = 0; q < 8; ++q) {
        int idx = base + q;
        if (idx < GSIZE) {
            int node = g * GSIZE + idx;
            rowstart[node] = run;
            float d = fmaxf((float)v[q], 1.f);
            dinv[node] = rsqrtf(d);
            sdeg[node] = sqrtf(d);
            run += v[q];
        }
    }
    if (tid == 0) rowstart[g * GSIZE + GSIZE] = goff_s + n;  // == next graph's start
}

// ---------------- phase B: build csrc in LDS, write coalesced ----------------------
__global__ __launch_bounds__(256) void k_binB(
    const unsigned* __restrict__ gbuf, const int* __restrict__ gcur,
    const int* __restrict__ rowstart, int* __restrict__ csrc) {
    __shared__ int lcur[500];
    __shared__ int stage[STAGE_CAP];
    int B = blockIdx.x; int k = B & 7, j = B >> 3;
    int gi = j >> 2, q = j & 3;
    int g = graph_of(k, gi);
    if (g < 0) return;
    int tid = threadIdx.x;
    int n0 = g * GSIZE + q * 500;
    int n0l = q * 500;
    int span0 = rowstart[n0];
    int span  = rowstart[n0 + 500] - span0;
    for (int i = tid; i < 500; i += 256) lcur[i] = rowstart[n0 + i] - span0;
    __syncthreads();
    int n = gcur[g];
    const unsigned* bp = gbuf + (size_t)g * BCAP;
    for (int i = tid; i < n; i += 256) {
        unsigned v = bp[i];
        unsigned d = (v & 2047u) - (unsigned)n0l;
        if (d < 500u) {
            int p = atomicAdd(&lcur[d], 1);
            stage[p] = (int)(v >> 11);
        }
    }
    __syncthreads();
    for (int s = tid; s < span; s += 256)
        csrc[span0 + s] = stage[s];
}

// ---------------- convert: Yh = bf16(dinv * x) (XCD-pinned per graph) --------------
__global__ __launch_bounds__(256) void k_convert(const float* __restrict__ x,
                          const float* __restrict__ dinv, ushort* __restrict__ Yh) {
    int B = blockIdx.x; int k = B & 7, j = B >> 3;
    int gi = j / 250, local = j % 250;
    int g = graph_of(k, gi);
    if (g < 0) return;
    int tid = threadIdx.x;
    int r = tid >> 5, c = tid & 31;
    int node = g * GSIZE + local * 8 + r;
    float dv = dinv[node];
    float4 v = ((const float4*)x)[node * 32 + c];
    uint2 yo;
    yo.x = bf16rnd(v.x * dv) | (bf16rnd(v.y * dv) << 16);
    yo.y = bf16rnd(v.z * dv) | (bf16rnd(v.w * dv) << 16);
    ((uint2*)Yh)[node * 32 + c] = yo;
}

// ---------------- pack W1+W2 (256x128 each) into MFMA B-fragment layout, hi/lo -----
__global__ void k_packW(const float* __restrict__ W1, const float* __restrict__ W2,
                        ushort* __restrict__ W1h, ushort* __restrict__ W1l,
                        ushort* __restrict__ W2h, ushort* __restrict__ W2l) {
    int b = blockIdx.x;                          // 0..255; 128 blocks per W
    const float* W = (b < 128) ? W1 : W2;
    ushort* Wh = (b < 128) ? W1h : W2h;
    ushort* Wl = (b < 128) ? W1l : W2l;
    int idx = (b & 127) * 256 + threadIdx.x;     // 0..32767
    int j = idx & 7, l = (idx >> 3) & 63, kb = (idx >> 9) & 7, c = idx >> 12;
    int k = kb * 32 + (l >> 4) * 8 + j;
    int col = c * 16 + (l & 15);
    float w = W[k * 128 + col];
    unsigned h = bf16rnd(w);
    float rem = w - __uint_as_float(h << 16);
    Wh[idx] = (ushort)h;
    Wl[idx] = (ushort)bf16rnd(rem);
}

// ---------------- gather: T[n] = bf16( -dinv[n] * sum_e Yh[csrc[e]] ) --------------
// XCD-pinned: 16 nodes/block, 16 lanes/node, 16B loads. Row = 16 uint4 (256 B).
// 4-edge software pipeline: 4 independent row-load/accumulate streams for MLP.
__device__ __forceinline__ void acc8(float* a, uint4 u) {
    a[0] += blo(u.x); a[1] += bhi(u.x); a[2] += blo(u.y); a[3] += bhi(u.y);
    a[4] += blo(u.z); a[5] += bhi(u.z); a[6] += blo(u.w); a[7] += bhi(u.w);
}
__global__ __launch_bounds__(256) void k_gather(
    const ushort* __restrict__ Yh, const float* __restrict__ dinv,
    const int* __restrict__ rowstart, const int* __restrict__ csrc,
    ushort* __restrict__ Th) {
    int B = blockIdx.x; int k = B & 7, j = B >> 3;
    int gi = j / 125, local = j % 125;
    int g = graph_of(k, gi);
    if (g < 0) return;
    int tid = threadIdx.x;
    int c = tid & 15;          // 16B column group 0..15
    int i = tid >> 4;          // node 0..15
    int n = g * GSIZE + local * 16 + i;
    int rs = rowstart[n], re = rowstart[n + 1];
    const uint4* Y4 = (const uint4*)Yh;
    float a0[8] = {0.f}, a1[8] = {0.f}, a2[8] = {0.f}, a3[8] = {0.f};
    int e = rs;
    for (; e + 3 < re; e += 4) {
        int s0 = csrc[e], s1 = csrc[e + 1], s2 = csrc[e + 2], s3 = csrc[e + 3];
        uint4 u0 = Y4[s0 * 16 + c];
        uint4 u1 = Y4[s1 * 16 + c];
        uint4 u2 = Y4[s2 * 16 + c];
        uint4 u3 = Y4[s3 * 16 + c];
        acc8(a0, u0); acc8(a1, u1); acc8(a2, u2); acc8(a3, u3);
    }
    for (; e < re; ++e) {
        uint4 u = Y4[csrc[e] * 16 + c];
        acc8(a0, u);
    }
#pragma unroll
    for (int t = 0; t < 8; ++t) a0[t] = (a0[t] + a1[t]) + (a2[t] + a3[t]);
    float dn = -dinv[n];
    uint4 o;
    o.x = bf16rnd(a0[0] * dn) | (bf16rnd(a0[1] * dn) << 16);
    o.y = bf16rnd(a0[2] * dn) | (bf16rnd(a0[3] * dn) << 16);
    o.z = bf16rnd(a0[4] * dn) | (bf16rnd(a0[5] * dn) << 16);
    o.w = bf16rnd(a0[6] * dn) | (bf16rnd(a0[7] * dn) << 16);
    ((uint4*)Th)[n * 16 + c] = o;
}

// ---------------- MFMA GEMM (round-6 structure: 256 thr, 2 c-tiles/wave) ------------
// out = relu(sdeg_row*(Y@Wa) + T@Wb + b). Measured best of 6 structural variants
// (r5 55us / r6 47us / r8-r10 70us) — do not "improve" without counter evidence.
// mode 0: Oy = bf16(out * dinv[row]) -- MUST NOT alias Yh/Th (waves drift; no barrier).
// mode 1: fused segment-max into hg.
__global__ __launch_bounds__(256, 2) void k_gemm(
    const ushort* __restrict__ Yh, const ushort* __restrict__ Th,
    const ushort* __restrict__ Wh, const ushort* __restrict__ Wl,
    const float* __restrict__ bias, const float* __restrict__ dinv,
    const float* __restrict__ sdeg,
    ushort* __restrict__ Oy, float* __restrict__ hg, int mode) {
    int B = blockIdx.x; int k = B & 7, j = B >> 3;
    int gi = j / 25, local = j % 25;
    int g = graph_of(k, gi);
    if (g < 0) return;
    int tid = threadIdx.x;
    int lane = tid & 63, wave = tid >> 6;
    int m = lane & 15, quad = lane >> 4;
    int rowbase = g * GSIZE + local * 80;
    int col0 = wave * 16 + m, col1 = (wave + 4) * 16 + m;

    short8 bh[2][8], bl[2][8];
#pragma unroll
    for (int ci = 0; ci < 2; ++ci) {
        int c = wave + ci * 4;
#pragma unroll
        for (int kb = 0; kb < 8; ++kb) {
            int bo = ((c * 8 + kb) * 64 + lane) * 8;
            bh[ci][kb] = *reinterpret_cast<const short8*>(Wh + bo);
            bl[ci][kb] = *reinterpret_cast<const short8*>(Wl + bo);
        }
    }
    float bb0 = bias[col0], bb1 = bias[col1];
    float run0 = 0.f, run1 = 0.f;

#pragma unroll 1
    for (int rt = 0; rt < 5; ++rt) {
        int wrow = rowbase + rt * 16;
        int row = wrow + m;
        f32x4 aA0 = {0.f,0.f,0.f,0.f}, aB0 = {0.f,0.f,0.f,0.f};
        f32x4 aA1 = {0.f,0.f,0.f,0.f}, aB1 = {0.f,0.f,0.f,0.f};
#pragma unroll
        for (int kb = 0; kb < 4; ++kb) {
            int ko = kb * 32 + quad * 8;
            short8 aY = *reinterpret_cast<const short8*>(Yh + row * FEAT + ko);
            short8 aT = *reinterpret_cast<const short8*>(Th + row * FEAT + ko);
            aA0 = __builtin_amdgcn_mfma_f32_16x16x32_bf16(aY, bh[0][kb],     aA0, 0, 0, 0);
            aA0 = __builtin_amdgcn_mfma_f32_16x16x32_bf16(aY, bl[0][kb],     aA0, 0, 0, 0);
            aB0 = __builtin_amdgcn_mfma_f32_16x16x32_bf16(aT, bh[0][kb + 4], aB0, 0, 0, 0);
            aB0 = __builtin_amdgcn_mfma_f32_16x16x32_bf16(aT, bl[0][kb + 4], aB0, 0, 0, 0);
            aA1 = __builtin_amdgcn_mfma_f32_16x16x32_bf16(aY, bh[1][kb],     aA1, 0, 0, 0);
            aA1 = __builtin_amdgcn_mfma_f32_16x16x32_bf16(aY, bl[1][kb],     aA1, 0, 0, 0);
            aB1 = __builtin_amdgcn_mfma_f32_16x16x32_bf16(aT, bh[1][kb + 4], aB1, 0, 0, 0);
            aB1 = __builtin_amdgcn_mfma_f32_16x16x32_bf16(aT, bl[1][kb + 4], aB1, 0, 0, 0);
        }
        if (mode == 0) {
#pragma unroll
            for (int r = 0; r < 4; ++r) {
                int orow = wrow + quad * 4 + r;   // C/D: col = lane&15, row = quad*4 + reg
                float s = sdeg[orow], dv = dinv[orow];
                float v0 = fmaxf(aA0[r] * s + aB0[r] + bb0, 0.f);
                float v1 = fmaxf(aA1[r] * s + aB1[r] + bb1, 0.f);
                Oy[orow * FEAT + col0] = (ushort)bf16rnd(v0 * dv);
                Oy[orow * FEAT + col1] = (ushort)bf16rnd(v1 * dv);
            }
        } else {
#pragma unroll
            for (int r = 0; r < 4; ++r) {
                float s = sdeg[wrow + quad * 4 + r];
                run0 = fmaxf(run0, fmaxf(aA0[r] * s + aB0[r] + bb0, 0.f));
                run1 = fmaxf(run1, fmaxf(aA1[r] * s + aB1[r] + bb1, 0.f));
            }
        }
    }
    if (mode == 1) {
        run0 = fmaxf(run0, __shfl_xor(run0, 16));
        run0 = fmaxf(run0, __shfl_xor(run0, 32));
        run1 = fmaxf(run1, __shfl_xor(run1, 16));
        run1 = fmaxf(run1, __shfl_xor(run1, 32));
        if (lane < 16) {
            atomicMax((int*)&hg[g * FEAT + col0], __float_as_int(run0));  // vals >= 0, hg 0-init
            atomicMax((int*)&hg[g * FEAT + col1], __float_as_int(run1));
        }
    }
}

// ---------------- classifier ----------------
__global__ void k_classify(const float* __restrict__ hg, const float* __restrict__ Wc,
                           const float* __restrict__ bc, float* __restrict__ out) {
    int g = blockIdx.x, t = threadIdx.x;
    if (t < NC) {
        float acc = bc[t];
        for (int j = 0; j < FEAT; ++j) acc += hg[g * FEAT + j] * Wc[j * NC + t];
        out[g * NC + t] = acc;
    }
}

extern "C" void kernel_launch(void* const* d_in, const int* in_sizes, int n_in,
                              void* d_out, int out_size, void* d_ws, size_t ws_size,
                              hipStream_t stream) {
    const float* x   = (const float*)d_in[0];
    const float* W1  = (const float*)d_in[1];
    const float* b1  = (const float*)d_in[2];
    const float* W2  = (const float*)d_in[3];
    const float* b2  = (const float*)d_in[4];
    const float* Wc  = (const float*)d_in[5];
    const float* bc  = (const float*)d_in[6];
    const int*   src = (const int*)d_in[7];
    const int*   dst = (const int*)d_in[8];
    float* out = (float*)d_out;

    char* ws = (char*)d_ws;
    size_t off = 0;
    auto alloc = [&](size_t bytes) { char* p = ws + off; off += (bytes + 255) & ~(size_t)255; return p; };
    int*      gcur     = (int*)     alloc(NB * 4);            // contiguous with hg:
    float*    hg       = (float*)   alloc(NB * FEAT * 4);     // one memset covers both
    float*    dinv     = (float*)   alloc(N_NODES * 4);
    float*    sdeg     = (float*)   alloc(N_NODES * 4);
    int*      rowstart = (int*)     alloc((N_NODES + 1) * 4);
    unsigned* gbuf     = (unsigned*)alloc((size_t)NB * BCAP * 4);
    int*      csrc     = (int*)     alloc((size_t)N_EDGES * 4);
    ushort*   W1h      = (ushort*)  alloc(256 * 128 * 2);
    ushort*   W1l      = (ushort*)  alloc(256 * 128 * 2);
    ushort*   W2h      = (ushort*)  alloc(256 * 128 * 2);
    ushort*   W2l      = (ushort*)  alloc(256 * 128 * 2);
    ushort*   Yh       = (ushort*)  alloc((size_t)N_NODES * FEAT * 2);  // dinv*x (layer-1 A)
    ushort*   Y2h      = (ushort*)  alloc((size_t)N_NODES * FEAT * 2);  // dinv*h (layer-2 A)
    ushort*   Th       = (ushort*)  alloc((size_t)N_NODES * FEAT * 2);  // T1 -> T2

    hipMemsetAsync(gcur, 0, 256 + NB * FEAT * 4, stream);   // gcur + hg (adjacent)

    // CSR build
    k_binA<<<NBLK_A, 256, 0, stream>>>(src, dst, gbuf, gcur);
    k_prep<<<56, 256, 0, stream>>>(gbuf, gcur, rowstart, dinv, sdeg);
    k_binB<<<224, 256, 0, stream>>>(gbuf, gcur, rowstart, csrc);

    k_packW<<<256, 256, 0, stream>>>(W1, W2, W1h, W1l, W2h, W2l);
    k_convert<<<14000, 256, 0, stream>>>(x, dinv, Yh);

    // layer 1 (gemm writes dinv*h into Y2h -- distinct buffer, no intra-block race)
    k_gather<<<7000, 256, 0, stream>>>(Yh, dinv, rowstart, csrc, Th);
    k_gemm<<<1400, 256, 0, stream>>>(Yh, Th, W1h, W1l, b1, dinv, sdeg, Y2h, nullptr, 0);
    // layer 2 (fused segmax)
    k_gather<<<7000, 256, 0, stream>>>(Y2h, dinv, rowstart, csrc, Th);
    k_gemm<<<1400, 256, 0, stream>>>(Y2h, Th, W2h, W2l, b2, dinv, sdeg, nullptr, hg, 1);

    k_classify<<<NB, 64, 0, stream>>>(hg, Wc, bc, out);
}

// Round 12
// 336.752 us; speedup vs baseline: 1.1995x; 1.0425x over previous
//
#include <hip/hip_runtime.h>

#define N_NODES 100000
#define N_EDGES 1600000
#define NB      50
#define GSIZE   2000
#define FEAT    128
#define NC      10
#define NSB     400        // 50 graphs x 8 sub-buckets (250 dst-nodes each)
#define BCAP    5120       // per-sub-bucket capacity (mean 4000, sd ~63 -> 17 sigma)
#define CHUNK   2048       // edges per binA block
#define NBLK_A  782        // ceil(E / CHUNK)

using short8 = __attribute__((ext_vector_type(8))) short;
using f32x4  = __attribute__((ext_vector_type(4))) float;

__device__ __forceinline__ unsigned bf16rnd(float f) {
    unsigned u = __float_as_uint(f);
    return (u + 0x7fffu + ((u >> 16) & 1u)) >> 16;   // RNE bf16 bits
}
__device__ __forceinline__ float blo(unsigned w) { return __uint_as_float(w << 16); }
__device__ __forceinline__ float bhi(unsigned w) { return __uint_as_float(w & 0xffff0000u); }

// XCD-pinned graph mapping: assumes XCD = blockIdx % 8 round-robin.
// XCD k owns graphs {k, k+8, ..., k+40} plus graph 48 (k=0) / 49 (k=1).
__device__ __forceinline__ int graph_of(int k, int gi) {
    if (gi < 6) return k + 8 * gi;
    return (k < 2) ? (48 + k) : -1;
}

// ---------------- phase A: bin edges into 400 sub-buckets (LDS-staged) -------------
__global__ __launch_bounds__(256) void k_binA(
    const int* __restrict__ src, const int* __restrict__ dst,
    unsigned* __restrict__ gbuf, int* __restrict__ gcur) {
    __shared__ int cnt[NSB];
    __shared__ int base[NSB];
    __shared__ int gbase[NSB];
    __shared__ int tsum[256];
    __shared__ unsigned stage[CHUNK];
    __shared__ unsigned short bslot[CHUNK];
    __shared__ int total_s;
    int tid = threadIdx.x;
    int e0 = blockIdx.x * CHUNK;
    for (int i = tid; i < NSB; i += 256) cnt[i] = 0;
    __syncthreads();

    unsigned pv[8]; int pb[8], pr[8];
#pragma unroll
    for (int q = 0; q < 8; ++q) {
        int e = e0 + q * 256 + tid;
        pb[q] = -1;
        if (e < N_EDGES) {
            int d = dst[e];
            int g = d / 2000;                 // magic-mul
            int l = d - g * 2000;
            int sb = g * 8 + l / 250;         // magic-mul
            pv[q] = ((unsigned)src[e] << 11) | (unsigned)l;
            pb[q] = sb;
            pr[q] = atomicAdd(&cnt[sb], 1);
        }
    }
    __syncthreads();
    // parallel exclusive scan of cnt[400] (2 entries/thread + Hillis-Steele)
    int v0 = (2 * tid     < NSB) ? cnt[2 * tid]     : 0;
    int v1 = (2 * tid + 1 < NSB) ? cnt[2 * tid + 1] : 0;
    int loc = v0 + v1;
    tsum[tid] = loc; __syncthreads();
    for (int off = 1; off < 256; off <<= 1) {
        int t = (tid >= off) ? tsum[tid - off] : 0;
        __syncthreads(); tsum[tid] += t; __syncthreads();
    }
    int pref = tsum[tid] - loc;
    if (2 * tid     < NSB) base[2 * tid]     = pref;
    if (2 * tid + 1 < NSB) base[2 * tid + 1] = pref + v0;
    if (tid == 255) total_s = tsum[255];
    __syncthreads();
#pragma unroll
    for (int q = 0; q < 8; ++q) {
        if (pb[q] >= 0) {
            int s = base[pb[q]] + pr[q];
            stage[s] = pv[q];
            bslot[s] = (unsigned short)pb[q];
        }
    }
    for (int b = tid; b < NSB; b += 256) gbase[b] = atomicAdd(&gcur[b], cnt[b]);
    __syncthreads();
    int total = total_s;
    for (int s = tid; s < total; s += 256) {
        int b = bslot[s];
        gbuf[(size_t)b * BCAP + gbase[b] + (s - base[b])] = stage[s];
    }
}

// ---------------- per-graph: hist + scan -> rowstart, dinv, sdeg -------------------
__global__ __launch_bounds__(256) void k_prep(
    const unsigned* __restrict__ gbuf, const int* __restrict__ gcur,
    int* __restrict__ rowstart, float* __restrict__ dinv, float* __restrict__ sdeg) {
    __shared__ int hist[GSIZE];
    __shared__ int tsum[256];
    __shared__ int goff_s, ntot_s;
    int B = blockIdx.x; int k = B & 7, gi = B >> 3;
    int g = graph_of(k, gi);
    if (g < 0) return;
    int tid = threadIdx.x;
    for (int i = tid; i < GSIZE; i += 256) hist[i] = 0;
    // goff = sum gcur[0 .. g*8) -- parallel reduce (serial tid0 loop would cost ~25us)
    {
        int acc = 0;
        for (int i = tid; i < g * 8; i += 256) acc += gcur[i];
        tsum[tid] = acc; __syncthreads();
        for (int off = 128; off > 0; off >>= 1) {
            if (tid < off) tsum[tid] += tsum[tid + off];
            __syncthreads();
        }
        if (tid == 0) {
            goff_s = tsum[0];
            int nt = 0;
            for (int q = 0; q < 8; ++q) nt += gcur[g * 8 + q];
            ntot_s = nt;
        }
        __syncthreads();
    }
    for (int q = 0; q < 8; ++q) {
        int nq = gcur[g * 8 + q];
        const unsigned* bp = gbuf + (size_t)(g * 8 + q) * BCAP;
        for (int i = tid; i < nq; i += 256) atomicAdd(&hist[bp[i] & 2047u], 1);
    }
    __syncthreads();
    int base = tid * 8;
    int v[8]; int loc = 0;
#pragma unroll
    for (int q = 0; q < 8; ++q) {
        int idx = base + q;
        v[q] = (idx < GSIZE) ? hist[idx] : 0;
        loc += v[q];
    }
    tsum[tid] = loc; __syncthreads();
    for (int off = 1; off < 256; off <<= 1) {
        int t = (tid >= off) ? tsum[tid - off] : 0;
        __syncthreads(); tsum[tid] += t; __syncthreads();
    }
    int run = goff_s + tsum[tid] - loc;
#pragma unroll
    for (int q = 0; q < 8; ++q) {
        int idx = base + q;
        if (idx < GSIZE) {
            int node = g * GSIZE + idx;
            rowstart[node] = run;
            float d = fmaxf((float)v[q], 1.f);
            dinv[node] = rsqrtf(d);
            sdeg[node] = sqrtf(d);
            run += v[q];
        }
    }
    if (tid == 0) rowstart[g * GSIZE + GSIZE] = goff_s + ntot_s;
}

// ---------------- phase B: build csrc in LDS, write coalesced ----------------------
// One block per sub-bucket (250 dst nodes, ~4000 edges): no filtering, small cursors.
__global__ __launch_bounds__(256) void k_binB(
    const unsigned* __restrict__ gbuf, const int* __restrict__ gcur,
    const int* __restrict__ rowstart, int* __restrict__ csrc) {
    __shared__ int lcur[250];
    __shared__ int stage[BCAP];
    int B = blockIdx.x; int k = B & 7, j = B >> 3;
    int gi = j >> 3, q = j & 7;
    int g = graph_of(k, gi);
    if (g < 0) return;
    int tid = threadIdx.x;
    int n0 = g * GSIZE + q * 250;
    int n0l = q * 250;
    int span0 = rowstart[n0];
    int n4 = gcur[g * 8 + q];                 // == span of these 250 nodes
    for (int i = tid; i < 250; i += 256) lcur[i] = rowstart[n0 + i] - span0;
    __syncthreads();
    const unsigned* bp = gbuf + (size_t)(g * 8 + q) * BCAP;
    for (int i = tid; i < n4; i += 256) {
        unsigned v = bp[i];
        int d = (int)(v & 2047u) - n0l;
        int p = atomicAdd(&lcur[d], 1);
        stage[p] = (int)(v >> 11);
    }
    __syncthreads();
    for (int s = tid; s < n4; s += 256)
        csrc[span0 + s] = stage[s];
}

// ---------------- convert: Yh = bf16(dinv * x) (XCD-pinned per graph) --------------
__global__ __launch_bounds__(256) void k_convert(const float* __restrict__ x,
                          const float* __restrict__ dinv, ushort* __restrict__ Yh) {
    int B = blockIdx.x; int k = B & 7, j = B >> 3;
    int gi = j / 250, local = j % 250;
    int g = graph_of(k, gi);
    if (g < 0) return;
    int tid = threadIdx.x;
    int r = tid >> 5, c = tid & 31;
    int node = g * GSIZE + local * 8 + r;
    float dv = dinv[node];
    float4 v = ((const float4*)x)[node * 32 + c];
    uint2 yo;
    yo.x = bf16rnd(v.x * dv) | (bf16rnd(v.y * dv) << 16);
    yo.y = bf16rnd(v.z * dv) | (bf16rnd(v.w * dv) << 16);
    ((uint2*)Yh)[node * 32 + c] = yo;
}

// ---------------- pack W1+W2 (256x128 each) into MFMA B-fragment layout, hi/lo -----
__global__ void k_packW(const float* __restrict__ W1, const float* __restrict__ W2,
                        ushort* __restrict__ W1h, ushort* __restrict__ W1l,
                        ushort* __restrict__ W2h, ushort* __restrict__ W2l) {
    int b = blockIdx.x;                          // 0..255; 128 blocks per W
    const float* W = (b < 128) ? W1 : W2;
    ushort* Wh = (b < 128) ? W1h : W2h;
    ushort* Wl = (b < 128) ? W1l : W2l;
    int idx = (b & 127) * 256 + threadIdx.x;     // 0..32767
    int j = idx & 7, l = (idx >> 3) & 63, kb = (idx >> 9) & 7, c = idx >> 12;
    int k = kb * 32 + (l >> 4) * 8 + j;
    int col = c * 16 + (l & 15);
    float w = W[k * 128 + col];
    unsigned h = bf16rnd(w);
    float rem = w - __uint_as_float(h << 16);
    Wh[idx] = (ushort)h;
    Wl[idx] = (ushort)bf16rnd(rem);
}

// ---------------- gather: T[n] = bf16( -dinv[n] * sum_e Yh[csrc[e]] ) --------------
// XCD-pinned: 16 nodes/block, 16 lanes/node, 16B loads. Row = 16 uint4 (256 B).
// 4-edge software pipeline: 4 independent row-load/accumulate streams for MLP.
__device__ __forceinline__ void acc8(float* a, uint4 u) {
    a[0] += blo(u.x); a[1] += bhi(u.x); a[2] += blo(u.y); a[3] += bhi(u.y);
    a[4] += blo(u.z); a[5] += bhi(u.z); a[6] += blo(u.w); a[7] += bhi(u.w);
}
__global__ __launch_bounds__(256) void k_gather(
    const ushort* __restrict__ Yh, const float* __restrict__ dinv,
    const int* __restrict__ rowstart, const int* __restrict__ csrc,
    ushort* __restrict__ Th) {
    int B = blockIdx.x; int k = B & 7, j = B >> 3;
    int gi = j / 125, local = j % 125;
    int g = graph_of(k, gi);
    if (g < 0) return;
    int tid = threadIdx.x;
    int c = tid & 15;          // 16B column group 0..15
    int i = tid >> 4;          // node 0..15
    int n = g * GSIZE + local * 16 + i;
    int rs = rowstart[n], re = rowstart[n + 1];
    const uint4* Y4 = (const uint4*)Yh;
    float a0[8] = {0.f}, a1[8] = {0.f}, a2[8] = {0.f}, a3[8] = {0.f};
    int e = rs;
    for (; e + 3 < re; e += 4) {
        int s0 = csrc[e], s1 = csrc[e + 1], s2 = csrc[e + 2], s3 = csrc[e + 3];
        uint4 u0 = Y4[s0 * 16 + c];
        uint4 u1 = Y4[s1 * 16 + c];
        uint4 u2 = Y4[s2 * 16 + c];
        uint4 u3 = Y4[s3 * 16 + c];
        acc8(a0, u0); acc8(a1, u1); acc8(a2, u2); acc8(a3, u3);
    }
    for (; e < re; ++e) {
        uint4 u = Y4[csrc[e] * 16 + c];
        acc8(a0, u);
    }
#pragma unroll
    for (int t = 0; t < 8; ++t) a0[t] = (a0[t] + a1[t]) + (a2[t] + a3[t]);
    float dn = -dinv[n];
    uint4 o;
    o.x = bf16rnd(a0[0] * dn) | (bf16rnd(a0[1] * dn) << 16);
    o.y = bf16rnd(a0[2] * dn) | (bf16rnd(a0[3] * dn) << 16);
    o.z = bf16rnd(a0[4] * dn) | (bf16rnd(a0[5] * dn) << 16);
    o.w = bf16rnd(a0[6] * dn) | (bf16rnd(a0[7] * dn) << 16);
    ((uint4*)Th)[n * 16 + c] = o;
}

// ---------------- MFMA GEMM (round-6 structure: 256 thr, 2 c-tiles/wave) ------------
// out = relu(sdeg_row*(Y@Wa) + T@Wb + b). Measured best of 6 structural variants
// (r5 55us / r6 47us / r8-r10 70us) — do not "improve" without counter evidence.
// mode 0: Oy = bf16(out * dinv[row]) -- MUST NOT alias Yh/Th (waves drift; no barrier).
// mode 1: fused segment-max into hg.
__global__ __launch_bounds__(256, 2) void k_gemm(
    const ushort* __restrict__ Yh, const ushort* __restrict__ Th,
    const ushort* __restrict__ Wh, const ushort* __restrict__ Wl,
    const float* __restrict__ bias, const float* __restrict__ dinv,
    const float* __restrict__ sdeg,
    ushort* __restrict__ Oy, float* __restrict__ hg, int mode) {
    int B = blockIdx.x; int k = B & 7, j = B >> 3;
    int gi = j / 25, local = j % 25;
    int g = graph_of(k, gi);
    if (g < 0) return;
    int tid = threadIdx.x;
    int lane = tid & 63, wave = tid >> 6;
    int m = lane & 15, quad = lane >> 4;
    int rowbase = g * GSIZE + local * 80;
    int col0 = wave * 16 + m, col1 = (wave + 4) * 16 + m;

    short8 bh[2][8], bl[2][8];
#pragma unroll
    for (int ci = 0; ci < 2; ++ci) {
        int c = wave + ci * 4;
#pragma unroll
        for (int kb = 0; kb < 8; ++kb) {
            int bo = ((c * 8 + kb) * 64 + lane) * 8;
            bh[ci][kb] = *reinterpret_cast<const short8*>(Wh + bo);
            bl[ci][kb] = *reinterpret_cast<const short8*>(Wl + bo);
        }
    }
    float bb0 = bias[col0], bb1 = bias[col1];
    float run0 = 0.f, run1 = 0.f;

#pragma unroll 1
    for (int rt = 0; rt < 5; ++rt) {
        int wrow = rowbase + rt * 16;
        int row = wrow + m;
        f32x4 aA0 = {0.f,0.f,0.f,0.f}, aB0 = {0.f,0.f,0.f,0.f};
        f32x4 aA1 = {0.f,0.f,0.f,0.f}, aB1 = {0.f,0.f,0.f,0.f};
#pragma unroll
        for (int kb = 0; kb < 4; ++kb) {
            int ko = kb * 32 + quad * 8;
            short8 aY = *reinterpret_cast<const short8*>(Yh + row * FEAT + ko);
            short8 aT = *reinterpret_cast<const short8*>(Th + row * FEAT + ko);
            aA0 = __builtin_amdgcn_mfma_f32_16x16x32_bf16(aY, bh[0][kb],     aA0, 0, 0, 0);
            aA0 = __builtin_amdgcn_mfma_f32_16x16x32_bf16(aY, bl[0][kb],     aA0, 0, 0, 0);
            aB0 = __builtin_amdgcn_mfma_f32_16x16x32_bf16(aT, bh[0][kb + 4], aB0, 0, 0, 0);
            aB0 = __builtin_amdgcn_mfma_f32_16x16x32_bf16(aT, bl[0][kb + 4], aB0, 0, 0, 0);
            aA1 = __builtin_amdgcn_mfma_f32_16x16x32_bf16(aY, bh[1][kb],     aA1, 0, 0, 0);
            aA1 = __builtin_amdgcn_mfma_f32_16x16x32_bf16(aY, bl[1][kb],     aA1, 0, 0, 0);
            aB1 = __builtin_amdgcn_mfma_f32_16x16x32_bf16(aT, bh[1][kb + 4], aB1, 0, 0, 0);
            aB1 = __builtin_amdgcn_mfma_f32_16x16x32_bf16(aT, bl[1][kb + 4], aB1, 0, 0, 0);
        }
        if (mode == 0) {
#pragma unroll
            for (int r = 0; r < 4; ++r) {
                int orow = wrow + quad * 4 + r;   // C/D: col = lane&15, row = quad*4 + reg
                float s = sdeg[orow], dv = dinv[orow];
                float v0 = fmaxf(aA0[r] * s + aB0[r] + bb0, 0.f);
                float v1 = fmaxf(aA1[r] * s + aB1[r] + bb1, 0.f);
                Oy[orow * FEAT + col0] = (ushort)bf16rnd(v0 * dv);
                Oy[orow * FEAT + col1] = (ushort)bf16rnd(v1 * dv);
            }
        } else {
#pragma unroll
            for (int r = 0; r < 4; ++r) {
                float s = sdeg[wrow + quad * 4 + r];
                run0 = fmaxf(run0, fmaxf(aA0[r] * s + aB0[r] + bb0, 0.f));
                run1 = fmaxf(run1, fmaxf(aA1[r] * s + aB1[r] + bb1, 0.f));
            }
        }
    }
    if (mode == 1) {
        run0 = fmaxf(run0, __shfl_xor(run0, 16));
        run0 = fmaxf(run0, __shfl_xor(run0, 32));
        run1 = fmaxf(run1, __shfl_xor(run1, 16));
        run1 = fmaxf(run1, __shfl_xor(run1, 32));
        if (lane < 16) {
            atomicMax((int*)&hg[g * FEAT + col0], __float_as_int(run0));  // vals >= 0, hg 0-init
            atomicMax((int*)&hg[g * FEAT + col1], __float_as_int(run1));
        }
    }
}

// ---------------- classifier ----------------
__global__ void k_classify(const float* __restrict__ hg, const float* __restrict__ Wc,
                           const float* __restrict__ bc, float* __restrict__ out) {
    int g = blockIdx.x, t = threadIdx.x;
    if (t < NC) {
        float acc = bc[t];
        for (int j = 0; j < FEAT; ++j) acc += hg[g * FEAT + j] * Wc[j * NC + t];
        out[g * NC + t] = acc;
    }
}

extern "C" void kernel_launch(void* const* d_in, const int* in_sizes, int n_in,
                              void* d_out, int out_size, void* d_ws, size_t ws_size,
                              hipStream_t stream) {
    const float* x   = (const float*)d_in[0];
    const float* W1  = (const float*)d_in[1];
    const float* b1  = (const float*)d_in[2];
    const float* W2  = (const float*)d_in[3];
    const float* b2  = (const float*)d_in[4];
    const float* Wc  = (const float*)d_in[5];
    const float* bc  = (const float*)d_in[6];
    const int*   src = (const int*)d_in[7];
    const int*   dst = (const int*)d_in[8];
    float* out = (float*)d_out;

    char* ws = (char*)d_ws;
    size_t off = 0;
    auto alloc = [&](size_t bytes) { char* p = ws + off; off += (bytes + 255) & ~(size_t)255; return p; };
    int*      gcur     = (int*)     alloc(NSB * 4);           // contiguous with hg:
    float*    hg       = (float*)   alloc(NB * FEAT * 4);     // one memset covers both
    float*    dinv     = (float*)   alloc(N_NODES * 4);
    float*    sdeg     = (float*)   alloc(N_NODES * 4);
    int*      rowstart = (int*)     alloc((N_NODES + 1) * 4);
    unsigned* gbuf     = (unsigned*)alloc((size_t)NSB * BCAP * 4);
    int*      csrc     = (int*)     alloc((size_t)N_EDGES * 4);
    ushort*   W1h      = (ushort*)  alloc(256 * 128 * 2);
    ushort*   W1l      = (ushort*)  alloc(256 * 128 * 2);
    ushort*   W2h      = (ushort*)  alloc(256 * 128 * 2);
    ushort*   W2l      = (ushort*)  alloc(256 * 128 * 2);
    ushort*   Yh       = (ushort*)  alloc((size_t)N_NODES * FEAT * 2);  // dinv*x (layer-1 A)
    ushort*   Y2h      = (ushort*)  alloc((size_t)N_NODES * FEAT * 2);  // dinv*h (layer-2 A)
    ushort*   Th       = (ushort*)  alloc((size_t)N_NODES * FEAT * 2);  // T1 -> T2

    hipMemsetAsync(gcur, 0, 1792 + NB * FEAT * 4, stream);   // gcur(padded) + hg

    // CSR build (sub-bucketed counting sort)
    k_binA<<<NBLK_A, 256, 0, stream>>>(src, dst, gbuf, gcur);
    k_prep<<<56, 256, 0, stream>>>(gbuf, gcur, rowstart, dinv, sdeg);
    k_binB<<<448, 256, 0, stream>>>(gbuf, gcur, rowstart, csrc);

    k_packW<<<256, 256, 0, stream>>>(W1, W2, W1h, W1l, W2h, W2l);
    k_convert<<<14000, 256, 0, stream>>>(x, dinv, Yh);

    // layer 1 (gemm writes dinv*h into Y2h -- distinct buffer, no intra-block race)
    k_gather<<<7000, 256, 0, stream>>>(Yh, dinv, rowstart, csrc, Th);
    k_gemm<<<1400, 256, 0, stream>>>(Yh, Th, W1h, W1l, b1, dinv, sdeg, Y2h, nullptr, 0);
    // layer 2 (fused segmax)
    k_gather<<<7000, 256, 0, stream>>>(Y2h, dinv, rowstart, csrc, Th);
    k_gemm<<<1400, 256, 0, stream>>>(Y2h, Th, W2h, W2l, b2, dinv, sdeg, nullptr, hg, 1);

    k_classify<<<NB, 64, 0, stream>>>(hg, Wc, bc, out);
}